// Round 7
// baseline (345.233 us; speedup 1.0000x reference)
//
#include <hip/hip_runtime.h>
#include <hip/hip_bf16.h>

#define BB 4
#define NN 4096
#define EE 65536
#define FIN 128
#define FOUT 64
#define CAP 64
#define GRID 256

// grid-wide barrier. Safety: GRID=256 = 1 block/CU needed; LDS (33.3KB) allows 4
// blocks/CU and __launch_bounds__(256,2) caps VGPR at 128 (>=2 blocks/CU), so
// co-residency has >=2x margin. Probe with RMW (never served from stale L1);
// AGENT scope acq/rel gives cross-XCD visibility of all pre-barrier writes.
__device__ __forceinline__ void gbar(unsigned* c) {
    __syncthreads();
    if (threadIdx.x == 0) {
        __hip_atomic_fetch_add(c, 1u, __ATOMIC_ACQ_REL, __HIP_MEMORY_SCOPE_AGENT);
        while (__hip_atomic_fetch_add(c, 0u, __ATOMIC_ACQUIRE,
                                      __HIP_MEMORY_SCOPE_AGENT) < (unsigned)GRID)
            __builtin_amdgcn_s_sleep(8);
    }
    __syncthreads();
}

// zero the 3 barrier counters + base accumulator (ws is poisoned, not zeroed)
__global__ void init_kernel(unsigned* __restrict__ bar, float* __restrict__ base) {
    if (threadIdx.x < 3) bar[threadIdx.x] = 0u;
    base[threadIdx.x] = 0.f;   // 256 entries = BB*FOUT
}

__global__ __launch_bounds__(256, 2) void fused(
        const float* __restrict__ h, const int* __restrict__ ei,
        const float* __restrict__ W, const float* __restrict__ a,
        float* __restrict__ out, float* __restrict__ Wh, int* __restrict__ csr,
        int* __restrict__ deg, unsigned* __restrict__ flag, float* __restrict__ D,
        float* __restrict__ as_, float* __restrict__ at_, float* __restrict__ base,
        unsigned* __restrict__ bar) {
    __shared__ union {
        struct { float hs[32][132]; float Ws[64][64]; } wh;   // 33280 B
        float Wa[256];
        float red[4][64];
    } smem;
    int tid = threadIdx.x;
    int bid = blockIdx.x;
    int lane = tid & 63, wv = tid >> 6;

    // ---------------- P0: zero slices + Wh GEMM (2 tiles/block) + Wa + as/at ------
    {
        int gz = bid * 256 + tid;                     // blocks 0..63 cover 16384
        if (gz < BB * NN) { deg[gz] = 0; flag[gz] = 0u; D[gz] = 0.f; }

        int tx = tid & 15, ty = tid >> 4;
        int c0 = tx * 4, r0 = ty * 2;
        for (int tile = bid; tile < 512; tile += GRID) {
            __syncthreads();                           // prev tile's smem reads done
            long row0 = (long)tile * 32;
            for (int i = tid; i < 1024; i += 256) {    // h tile: 32x128
                float4 v = ((const float4*)(h + row0 * FIN))[i];
                int r = (i * 4) >> 7, c = (i * 4) & 127;
                *(float4*)&smem.wh.hs[r][c] = v;
            }
            float acc[2][4] = {};
            for (int kk = 0; kk < 128; kk += 64) {
                __syncthreads();                       // hs ready / Ws reusable
                for (int i = tid; i < 1024; i += 256) {
                    float4 v = ((const float4*)(W + kk * FOUT))[i];
                    int k = (i * 4) >> 6, c = (i * 4) & 63;
                    *(float4*)&smem.wh.Ws[k][c] = v;
                }
                __syncthreads();
#pragma unroll
                for (int k = 0; k < 64; k += 4) {
                    float4 w0 = *(const float4*)&smem.wh.Ws[k][c0];
                    float4 w1 = *(const float4*)&smem.wh.Ws[k + 1][c0];
                    float4 w2 = *(const float4*)&smem.wh.Ws[k + 2][c0];
                    float4 w3 = *(const float4*)&smem.wh.Ws[k + 3][c0];
#pragma unroll
                    for (int r = 0; r < 2; ++r) {
                        float4 hv = *(const float4*)&smem.wh.hs[r0 + r][kk + k];
                        acc[r][0] += hv.x * w0.x + hv.y * w1.x + hv.z * w2.x + hv.w * w3.x;
                        acc[r][1] += hv.x * w0.y + hv.y * w1.y + hv.z * w2.y + hv.w * w3.y;
                        acc[r][2] += hv.x * w0.z + hv.y * w1.z + hv.z * w2.z + hv.w * w3.z;
                        acc[r][3] += hv.x * w0.w + hv.y * w1.w + hv.z * w2.w + hv.w * w3.w;
                    }
                }
            }
#pragma unroll
            for (int r = 0; r < 2; ++r)
                *(float4*)&Wh[(row0 + r0 + r) * FOUT + c0] = *(float4*)&acc[r][0];
        }
        __syncthreads();                               // all smem reads done
        {   // per-block Wa = [W.a1 ; W.a2] (2x128), 64 FMA/thread
            int half = tid >> 7, k = tid & 127;
            const float* wr = W + k * FOUT;
            const float* av = a + half * FOUT;
            float s = 0.f;
#pragma unroll
            for (int f2 = 0; f2 < FOUT; ++f2) s += wr[f2] * av[f2];
            smem.Wa[half * 128 + k] = s;
        }
        __syncthreads();
#pragma unroll
        for (int r = 0; r < 4; ++r) {                  // 16 rows/block -> 4096 rows
            int n = bid * 16 + wv * 4 + r;
            float h0v = h[(long)n * FIN + lane];
            float h1v = h[(long)n * FIN + 64 + lane];
            float ps = h0v * smem.Wa[lane] + h1v * smem.Wa[64 + lane];
            float pt = h0v * smem.Wa[128 + lane] + h1v * smem.Wa[192 + lane];
            for (int off = 32; off; off >>= 1) {
                ps += __shfl_down(ps, off);
                pt += __shfl_down(pt, off);
            }
            if (lane == 0) { as_[n] = ps; at_[n] = pt; }
        }
    }
    gbar(&bar[0]);

    // ---------------- P1: edge pass (4 edges/thread, b = batch) ----------------
#pragma unroll
    for (int b = 0; b < BB; ++b) {
        int j = bid * 256 + tid;                       // 0..65535 (GRID*256 == EE)
        const int* eb = ei + (long)b * 2 * EE;
        int s = eb[j], t = eb[EE + j];
        float as_s = as_[s];
        if (as_s + at_[t] > 0.f) {
            flag[(b << 12) | t] = 1u;                  // racy same-value store: fine
            int row = (b << 12) | s;
            int slot = atomicAdd(&deg[row], 1);
            if (slot < CAP) csr[row * CAP + slot] = t;
        }
    }
    gbar(&bar[1]);

    // ---------------- P2: in-wave dedup + denominator (16 rows/wave); base on bid<128
    for (int i = 0; i < 16; ++i) {
        int row = bid * 64 + wv * 16 + i;              // 0..16383
        int b = row >> 12, s = row & 4095;
        int draw = min(deg[row], CAP);
        int t = -1;
        if (lane < draw) t = csr[row * CAP + lane];
        bool dup = false;
        for (int k = 0; k < draw; ++k) {
            int tk = __shfl(t, k);
            if (k < lane && tk == t) dup = true;
        }
        bool keep = (lane < draw) && !dup;
        unsigned long long mask = __ballot(keep);
        int pfx = __popcll(mask & ((1ull << lane) - 1ull));
        if (keep) {
            csr[row * CAP + pfx] = t;                  // compact in place
            atomicAdd(&D[(b << 12) | t], expf(as_[s]));   // no max-shift needed
        }
        if (lane == 0) deg[row] = __popcll(mask);
    }
    if (bid < 128) {                                   // base: 4 batches x 32 chunks
        int bb = bid >> 5, chunk = bid & 31;
        int f = tid & 63, ty = tid >> 6;
        float acc = 0.f;
        int t0 = chunk * (NN / 32);
        for (int tt = t0 + ty; tt < t0 + NN / 32; tt += 4)
            if (flag[(bb << 12) | tt] == 0u) acc += Wh[(((long)bb << 12) | tt) * FOUT + f];
        __syncthreads();
        smem.red[ty][f] = acc;
        __syncthreads();
        if (ty == 0)
            atomicAdd(&base[(bb << 6) | f],
                      (smem.red[0][f] + smem.red[1][f] + smem.red[2][f] + smem.red[3][f]) *
                          (1.0f / NN));
    }
    gbar(&bar[2]);

    // ---------------- P3: gather + ELU, 4 rows interleaved for MLP ----------------
    {
        int b = bid >> 6;                              // batch uniform per block
        const float* Whb = Wh + (((long)b << 12) * FOUT);
        const float* Db = D + (b << 12);
        float bs = base[(b << 6) | lane];
        for (int rr = 0; rr < 16; rr += 4) {
            int row0 = bid * 64 + wv * 16 + rr;
            int d0 = deg[row0], d1 = deg[row0 + 1], d2 = deg[row0 + 2], d3 = deg[row0 + 3];
            float E0 = expf(as_[row0 & 4095]), E1 = expf(as_[(row0 + 1) & 4095]);
            float E2 = expf(as_[(row0 + 2) & 4095]), E3 = expf(as_[(row0 + 3) & 4095]);
            const int* c0p = csr + (long)row0 * CAP;
            const int* c1p = c0p + CAP;
            const int* c2p = c1p + CAP;
            const int* c3p = c2p + CAP;
            float a0 = 0.f, a1 = 0.f, a2 = 0.f, a3 = 0.f;
            int dmax = max(max(d0, d1), max(d2, d3));
            for (int j = 0; j < dmax; ++j) {
                if (j < d0) { int t = c0p[j]; a0 += (E0 / Db[t]) * Whb[t * FOUT + lane]; }
                if (j < d1) { int t = c1p[j]; a1 += (E1 / Db[t]) * Whb[t * FOUT + lane]; }
                if (j < d2) { int t = c2p[j]; a2 += (E2 / Db[t]) * Whb[t * FOUT + lane]; }
                if (j < d3) { int t = c3p[j]; a3 += (E3 / Db[t]) * Whb[t * FOUT + lane]; }
            }
            float x0 = a0 + bs, x1 = a1 + bs, x2 = a2 + bs, x3 = a3 + bs;
            out[(long)row0 * FOUT + lane] = x0 > 0.f ? x0 : expm1f(x0);
            out[(long)(row0 + 1) * FOUT + lane] = x1 > 0.f ? x1 : expm1f(x1);
            out[(long)(row0 + 2) * FOUT + lane] = x2 > 0.f ? x2 : expm1f(x2);
            out[(long)(row0 + 3) * FOUT + lane] = x3 > 0.f ? x3 : expm1f(x3);
        }
    }
}

extern "C" void kernel_launch(void* const* d_in, const int* in_sizes, int n_in,
                              void* d_out, int out_size, void* d_ws, size_t ws_size,
                              hipStream_t stream) {
    const float* h  = (const float*)d_in[0];
    const int*   ei = (const int*)d_in[1];
    const float* W  = (const float*)d_in[2];
    const float* a  = (const float*)d_in[3];
    float* out = (float*)d_out;

    char* ws = (char*)d_ws;
    float*    Wh   = (float*)(ws);                       // 4 MiB
    int*      csr  = (int*)(ws + 4194304);               // 4 MiB (CAP=64)
    int*      deg  = (int*)(ws + 8388608);               // 64 KiB
    unsigned* flag = (unsigned*)(ws + 8454144);          // 64 KiB
    float*    D    = (float*)(ws + 8519680);             // 64 KiB
    float*    as_  = (float*)(ws + 8585216);             // 16 KiB
    float*    at_  = (float*)(ws + 8601600);             // 16 KiB
    float*    base = (float*)(ws + 8617984);             // 1 KiB
    unsigned* bar  = (unsigned*)(ws + 8619008);          // 3 uints

    init_kernel<<<1, 256, 0, stream>>>(bar, base);
    fused<<<GRID, 256, 0, stream>>>(h, ei, W, a, out, Wh, csr, deg, flag, D,
                                    as_, at_, base, bar);
}

// Round 8
// 104.450 us; speedup vs baseline: 3.3053x; 3.3053x over previous
//
#include <hip/hip_runtime.h>
#include <hip/hip_bf16.h>

#define BB 4
#define NN 4096
#define EE 65536
#define FIN 128
#define FOUT 64
#define CAP 64

// K_A: blocks 0..511 -> Wh GEMM (32-row tile, two-pass over K, 33KB LDS);
//      blocks 512..1023 -> zero bitmap/deg/D, compute Wa=[W.a1;W.a2], as/at.
__global__ __launch_bounds__(256) void phase0_kernel(
        const float* __restrict__ h, const float* __restrict__ W, const float* __restrict__ a,
        float* __restrict__ Wh, int* __restrict__ deg, float* __restrict__ D,
        unsigned* __restrict__ bitmap, float* __restrict__ as_, float* __restrict__ at_) {
    __shared__ union {
        struct { float hs[32][132]; float Ws[64][64]; } wh;   // 33280 B
        float Wa[256];
    } smem;
    int tid = threadIdx.x;
    int bid = blockIdx.x;
    if (bid < 512) {
        long row0 = (long)bid * 32;
        for (int i = tid; i < 1024; i += 256) {              // h tile: 32x128
            float4 v = ((const float4*)(h + row0 * FIN))[i];
            int r = (i * 4) >> 7, c = (i * 4) & 127;
            *(float4*)&smem.wh.hs[r][c] = v;
        }
        int tx = tid & 15, ty = tid >> 4;
        int c0 = tx * 4, r0 = ty * 2;
        float acc[2][4] = {};
        for (int kk = 0; kk < 128; kk += 64) {
            __syncthreads();                                  // hs ready / Ws reusable
            for (int i = tid; i < 1024; i += 256) {           // W rows kk..kk+63
                float4 v = ((const float4*)(W + kk * FOUT))[i];
                int k = (i * 4) >> 6, c = (i * 4) & 63;
                *(float4*)&smem.wh.Ws[k][c] = v;
            }
            __syncthreads();
#pragma unroll
            for (int k = 0; k < 64; k += 4) {
                float4 w0 = *(const float4*)&smem.wh.Ws[k][c0];
                float4 w1 = *(const float4*)&smem.wh.Ws[k + 1][c0];
                float4 w2 = *(const float4*)&smem.wh.Ws[k + 2][c0];
                float4 w3 = *(const float4*)&smem.wh.Ws[k + 3][c0];
#pragma unroll
                for (int r = 0; r < 2; ++r) {
                    float4 hv = *(const float4*)&smem.wh.hs[r0 + r][kk + k];
                    acc[r][0] += hv.x * w0.x + hv.y * w1.x + hv.z * w2.x + hv.w * w3.x;
                    acc[r][1] += hv.x * w0.y + hv.y * w1.y + hv.z * w2.y + hv.w * w3.y;
                    acc[r][2] += hv.x * w0.z + hv.y * w1.z + hv.z * w2.z + hv.w * w3.z;
                    acc[r][3] += hv.x * w0.w + hv.y * w1.w + hv.z * w2.w + hv.w * w3.w;
                }
            }
        }
#pragma unroll
        for (int r = 0; r < 2; ++r)
            *(float4*)&Wh[(row0 + r0 + r) * FOUT + c0] = *(float4*)&acc[r][0];
    } else {
        int local = bid - 512;                                // 0..511
        // zero bitmap slice: 4096 words = 1024 uint4 per block
        uint4* bm4 = (uint4*)(bitmap + (long)local * 4096);
        for (int i = tid; i < 1024; i += 256) bm4[i] = make_uint4(0u, 0u, 0u, 0u);
        int gid2 = local * 256 + tid;                         // 0..131071
        if (gid2 < BB * NN) { deg[gid2] = 0; D[gid2] = 0.f; }
        {   // per-block Wa = [W.a1 ; W.a2] (2x128), 64 FMA/thread
            int half = tid >> 7, k = tid & 127;
            const float* wr = W + k * FOUT;
            const float* av = a + half * FOUT;
            float s = 0.f;
#pragma unroll
            for (int f2 = 0; f2 < FOUT; ++f2) s += wr[f2] * av[f2];
            smem.Wa[half * 128 + k] = s;
        }
        __syncthreads();
        int lane = tid & 63, wv = tid >> 6;
#pragma unroll
        for (int r = 0; r < 2; ++r) {                         // 8 rows/block -> 4096 rows
            int n = local * 8 + wv * 2 + r;
            float h0v = h[(long)n * FIN + lane];
            float h1v = h[(long)n * FIN + 64 + lane];
            float ps = h0v * smem.Wa[lane] + h1v * smem.Wa[64 + lane];
            float pt = h0v * smem.Wa[128 + lane] + h1v * smem.Wa[192 + lane];
            for (int off = 32; off; off >>= 1) {
                ps += __shfl_down(ps, off);
                pt += __shfl_down(pt, off);
            }
            if (lane == 0) { as_[n] = ps; at_[n] = pt; }
        }
    }
}

// K_edge: one thread per edge. Bitmap first-touch dedup -> deduped CSR + D sum.
__global__ void edge_kernel(const int* __restrict__ ei, const float* __restrict__ as_,
                            const float* __restrict__ at_, unsigned* __restrict__ bitmap,
                            int* __restrict__ deg, int* __restrict__ csr,
                            float* __restrict__ D) {
    int idx = blockIdx.x * 256 + threadIdx.x;
    int b = idx >> 16;                 // EE = 65536
    int j = idx & 65535;
    const int* eb = ei + (long)b * 2 * EE;
    int s = eb[j], t = eb[EE + j];
    float as_s = as_[s];
    if (as_s + at_[t] > 0.f) {
        int row = (b << 12) | s;                       // b*NN + s
        long bit = ((long)row << 12) | t;
        unsigned m = 1u << (bit & 31);
        unsigned old = atomicOr(&bitmap[bit >> 5], m);
        if (!(old & m)) {                              // first occurrence of (b,s,t)
            atomicAdd(&D[(b << 12) | t], expf(as_s));  // no max-shift needed (|as|<~6)
            int slot = atomicAdd(&deg[row], 1);
            if (slot < CAP) csr[row * CAP + slot] = t;
        }
    }
}

// K_gather: 16 rows/block (4/wave interleaved). Inline base: columns with D==0.
__global__ __launch_bounds__(256) void gather_kernel(
        const int* __restrict__ deg, const int* __restrict__ csr,
        const float* __restrict__ as_, const float* __restrict__ D,
        const float* __restrict__ Wh, float* __restrict__ out) {
    __shared__ float bs[64];
    __shared__ int list[256];
    __shared__ int cnt;
    int tid = threadIdx.x;
    int lane = tid & 63, wv = tid >> 6;
    int bid = blockIdx.x;
    int b = bid >> 8;                                  // 256 blocks per batch
    const float* Db = D + (b << 12);
    const float* Whb = Wh + (((long)b << 12) * FOUT);
    if (tid == 0) cnt = 0;
    __syncthreads();
    for (int i = tid; i < NN; i += 256) {              // find no-positive-edge columns
        if (Db[i] == 0.f) {
            int p = atomicAdd(&cnt, 1);
            if (p < 256) list[p] = i;
        }
    }
    __syncthreads();
    if (wv == 0) {                                     // base vector (expected ~1-2 cols)
        int c = min(cnt, 256);
        float s = 0.f;
        for (int j = 0; j < c; ++j) s += Whb[list[j] * FOUT + lane];
        bs[lane] = s * (1.0f / NN);
    }
    __syncthreads();
    float bsv = bs[lane];

    int row0 = bid * 16 + wv * 4;                      // 4 rows per wave, interleaved
    int d0 = min(deg[row0], CAP), d1 = min(deg[row0 + 1], CAP);
    int d2 = min(deg[row0 + 2], CAP), d3 = min(deg[row0 + 3], CAP);
    float E0 = expf(as_[row0 & 4095]), E1 = expf(as_[(row0 + 1) & 4095]);
    float E2 = expf(as_[(row0 + 2) & 4095]), E3 = expf(as_[(row0 + 3) & 4095]);
    const int* c0p = csr + (long)row0 * CAP;
    const int* c1p = c0p + CAP;
    const int* c2p = c1p + CAP;
    const int* c3p = c2p + CAP;
    float a0 = 0.f, a1 = 0.f, a2 = 0.f, a3 = 0.f;
    int dmax = max(max(d0, d1), max(d2, d3));
    for (int j = 0; j < dmax; ++j) {
        if (j < d0) { int t = c0p[j]; a0 += (E0 / Db[t]) * Whb[t * FOUT + lane]; }
        if (j < d1) { int t = c1p[j]; a1 += (E1 / Db[t]) * Whb[t * FOUT + lane]; }
        if (j < d2) { int t = c2p[j]; a2 += (E2 / Db[t]) * Whb[t * FOUT + lane]; }
        if (j < d3) { int t = c3p[j]; a3 += (E3 / Db[t]) * Whb[t * FOUT + lane]; }
    }
    float x0 = a0 + bsv, x1 = a1 + bsv, x2 = a2 + bsv, x3 = a3 + bsv;
    out[(long)row0 * FOUT + lane] = x0 > 0.f ? x0 : expm1f(x0);
    out[(long)(row0 + 1) * FOUT + lane] = x1 > 0.f ? x1 : expm1f(x1);
    out[(long)(row0 + 2) * FOUT + lane] = x2 > 0.f ? x2 : expm1f(x2);
    out[(long)(row0 + 3) * FOUT + lane] = x3 > 0.f ? x3 : expm1f(x3);
}

extern "C" void kernel_launch(void* const* d_in, const int* in_sizes, int n_in,
                              void* d_out, int out_size, void* d_ws, size_t ws_size,
                              hipStream_t stream) {
    const float* h  = (const float*)d_in[0];
    const int*   ei = (const int*)d_in[1];
    const float* W  = (const float*)d_in[2];
    const float* a  = (const float*)d_in[3];
    float* out = (float*)d_out;

    char* ws = (char*)d_ws;
    float*    Wh     = (float*)(ws);                     // 4 MiB
    int*      csr    = (int*)(ws + 4194304);             // 4 MiB (CAP=64)
    unsigned* bitmap = (unsigned*)(ws + 8388608);        // 8 MiB
    int*      deg    = (int*)(ws + 16777216);            // 64 KiB
    float*    D      = (float*)(ws + 16842752);          // 64 KiB
    float*    as_    = (float*)(ws + 16908288);          // 16 KiB
    float*    at_    = (float*)(ws + 16924672);          // 16 KiB

    phase0_kernel<<<1024, 256, 0, stream>>>(h, W, a, Wh, deg, D, bitmap, as_, at_);
    edge_kernel<<<(BB * EE) / 256, 256, 0, stream>>>(ei, as_, at_, bitmap, deg, csr, D);
    gather_kernel<<<(BB * NN) / 16, 256, 0, stream>>>(deg, csr, as_, D, Wh, out);
}